// Round 1
// baseline (4700.152 us; speedup 1.0000x reference)
//
#include <hip/hip_runtime.h>
#include <math.h>

// Problem constants (from setup_inputs): T=64, B=1024, H=512, V=512
constexpr int T_STEPS = 64;
constexpr int B_SZ = 1024;
constexpr int H_SZ = 512;
constexpr int V_SZ = 512;
constexpr int G_SZ = 4 * H_SZ; // 2048

// ---------------------------------------------------------------------------
// Tiled NT SGEMM: C[M,N] = A[M,K] @ Bw[N,K]^T  (+bias1[n]) (+bias2[n])
//                 (+Add[tok[m]][n]  when USE_GATHER)
// A, Bw row-major with K contiguous (both operands K-fast -> "NT").
// BM=BN=64, BK=16, 256 threads, 4x4 micro-tile per thread.
// All problem dims here are multiples of 64/16 -> no bounds checks.
// ---------------------------------------------------------------------------
template <bool USE_BIAS2, bool USE_GATHER>
__global__ __launch_bounds__(256) void gemm_nt(
    const float* __restrict__ A, const float* __restrict__ Bw,
    float* __restrict__ C, int M, int N, int K,
    const float* __restrict__ bias1, const float* __restrict__ bias2,
    const float* __restrict__ Add, const int* __restrict__ tok)
{
    constexpr int BM = 64, BN = 64, BK = 16;
    __shared__ __align__(16) float As[BK][BM]; // stored transposed: As[k][m]
    __shared__ __align__(16) float Bs[BK][BN]; // Bs[k][n]

    const int tid = threadIdx.x;
    const int tx = tid % 16;   // n sub-tile
    const int ty = tid / 16;   // m sub-tile
    const int m0 = blockIdx.y * BM;
    const int n0 = blockIdx.x * BN;

    // loader mapping: each of 256 threads loads one float4 of the 64x16 tile
    const int lr = tid / 4;        // row within tile: 0..63
    const int lc = (tid % 4) * 4;  // k within tile: 0,4,8,12

    float acc[4][4] = {};

    for (int k0 = 0; k0 < K; k0 += BK) {
        const float4 av = *reinterpret_cast<const float4*>(
            &A[(size_t)(m0 + lr) * K + (k0 + lc)]);
        const float4 bv = *reinterpret_cast<const float4*>(
            &Bw[(size_t)(n0 + lr) * K + (k0 + lc)]);
        __syncthreads(); // previous iteration's reads complete before overwrite
        As[lc + 0][lr] = av.x; As[lc + 1][lr] = av.y;
        As[lc + 2][lr] = av.z; As[lc + 3][lr] = av.w;
        Bs[lc + 0][lr] = bv.x; Bs[lc + 1][lr] = bv.y;
        Bs[lc + 2][lr] = bv.z; Bs[lc + 3][lr] = bv.w;
        __syncthreads();
#pragma unroll
        for (int k = 0; k < BK; ++k) {
            const float4 a4 = *reinterpret_cast<const float4*>(&As[k][ty * 4]);
            const float4 b4 = *reinterpret_cast<const float4*>(&Bs[k][tx * 4]);
            const float ar[4] = {a4.x, a4.y, a4.z, a4.w};
            const float br[4] = {b4.x, b4.y, b4.z, b4.w};
#pragma unroll
            for (int i = 0; i < 4; ++i)
#pragma unroll
                for (int j = 0; j < 4; ++j)
                    acc[i][j] = fmaf(ar[i], br[j], acc[i][j]);
        }
    }

    // epilogue: per-column bias (float4), optional gathered row add, vector store
    const int nc = n0 + tx * 4;
    float4 bsum = make_float4(0.f, 0.f, 0.f, 0.f);
    if (bias1) {
        const float4 b1 = *reinterpret_cast<const float4*>(&bias1[nc]);
        bsum.x += b1.x; bsum.y += b1.y; bsum.z += b1.z; bsum.w += b1.w;
    }
    if (USE_BIAS2) {
        const float4 b2 = *reinterpret_cast<const float4*>(&bias2[nc]);
        bsum.x += b2.x; bsum.y += b2.y; bsum.z += b2.z; bsum.w += b2.w;
    }
#pragma unroll
    for (int i = 0; i < 4; ++i) {
        const int m = m0 + ty * 4 + i;
        float4 v;
        v.x = acc[i][0] + bsum.x;
        v.y = acc[i][1] + bsum.y;
        v.z = acc[i][2] + bsum.z;
        v.w = acc[i][3] + bsum.w;
        if (USE_GATHER) {
            const float* ap = Add + (size_t)tok[m] * N + nc;
            const float4 a4 = *reinterpret_cast<const float4*>(ap);
            v.x += a4.x; v.y += a4.y; v.z += a4.z; v.w += a4.w;
        }
        *reinterpret_cast<float4*>(&C[(size_t)m * N + nc]) = v;
    }
}

// ---------------------------------------------------------------------------
// Elementwise LSTM cell: gates[B,4H] (i,f,g,o) + c_in -> h_out, c_out
// ---------------------------------------------------------------------------
__global__ __launch_bounds__(256) void lstm_cell(
    const float* __restrict__ gates, const float* __restrict__ c_in,
    float* __restrict__ h_out, float* __restrict__ c_out)
{
    const int idx = blockIdx.x * blockDim.x + threadIdx.x; // b*H + k
    const int b = idx >> 9;        // / 512
    const int k = idx & (H_SZ - 1);
    const float* gr = gates + (size_t)b * G_SZ;
    const float ig = gr[k];
    const float fg = gr[H_SZ + k];
    const float gg = gr[2 * H_SZ + k];
    const float og = gr[3 * H_SZ + k];
    const float si = 1.f / (1.f + expf(-ig));
    const float sf = 1.f / (1.f + expf(-fg));
    const float so = 1.f / (1.f + expf(-og));
    const float tg = tanhf(gg);
    const float cn = sf * c_in[idx] + si * tg;
    c_out[idx] = cn;
    h_out[idx] = so * tanhf(cn);
}

// ---------------------------------------------------------------------------
// Row argmax over V=512 (first-index tie-break, matches np.argmax)
// one block per batch row
// ---------------------------------------------------------------------------
__global__ __launch_bounds__(256) void argmax_rows(
    const float* __restrict__ logits, int* __restrict__ tok_next)
{
    const int b = blockIdx.x;
    const int tid = threadIdx.x;
    const float* row = logits + (size_t)b * V_SZ;
    float bv = -INFINITY;
    int bi = 0;
    for (int v = tid; v < V_SZ; v += 256) { // ascending -> strict > keeps first
        const float x = row[v];
        if (x > bv) { bv = x; bi = v; }
    }
    __shared__ float sv[256];
    __shared__ int si[256];
    sv[tid] = bv; si[tid] = bi;
    __syncthreads();
    for (int s = 128; s > 0; s >>= 1) {
        if (tid < s) {
            const float ov = sv[tid + s];
            const int oi = si[tid + s];
            if (ov > sv[tid] || (ov == sv[tid] && oi < si[tid])) {
                sv[tid] = ov; si[tid] = oi;
            }
        }
        __syncthreads();
    }
    if (tid == 0) tok_next[b] = si[0];
}

__global__ __launch_bounds__(256) void init_tok(int* __restrict__ tok)
{
    tok[blockIdx.x * blockDim.x + threadIdx.x] = 0; // SOS_INDEX
}

// ---------------------------------------------------------------------------
extern "C" void kernel_launch(void* const* d_in, const int* in_sizes, int n_in,
                              void* d_out, int out_size, void* d_ws, size_t ws_size,
                              hipStream_t stream)
{
    // inputs: 0 target_var(int, unused), 1 target_max_len(unused, =64),
    // 2 encoder_hidden, 3 encoder_cell, 4 embedding, 5 W_ih, 6 W_hh,
    // 7 b_ih, 8 b_hh, 9 W_out, 10 b_out
    const float* enc_h = (const float*)d_in[2];
    const float* enc_c = (const float*)d_in[3];
    const float* emb   = (const float*)d_in[4];
    const float* W_ih  = (const float*)d_in[5];
    const float* W_hh  = (const float*)d_in[6];
    const float* b_ih  = (const float*)d_in[7];
    const float* b_hh  = (const float*)d_in[8];
    const float* W_out = (const float*)d_in[9];
    const float* b_out = (const float*)d_in[10];
    float* out = (float*)d_out;

    // workspace layout (floats)
    float* ws      = (float*)d_ws;
    float* E_gates = ws;                                   // V*G   = 1,048,576
    float* gates   = E_gates + (size_t)V_SZ * G_SZ;        // B*G   = 2,097,152
    float* hbuf    = gates + (size_t)B_SZ * G_SZ;          // 2*B*H
    float* cbuf    = hbuf + 2 * (size_t)B_SZ * H_SZ;       // 2*B*H
    int*   tokbuf  = (int*)(cbuf + 2 * (size_t)B_SZ * H_SZ); // 2*B ints

    const dim3 blk(256);

    // token[b] = SOS for step 0
    init_tok<<<B_SZ / 256, blk, 0, stream>>>(tokbuf);

    // E_gates = embedding @ W_ih^T + (b_ih + b_hh)   [V x 4H]
    gemm_nt<true, false><<<dim3(G_SZ / 64, V_SZ / 64), blk, 0, stream>>>(
        emb, W_ih, E_gates, V_SZ, G_SZ, H_SZ, b_ih, b_hh, nullptr, nullptr);

    const float* hp = enc_h;
    const float* cp = enc_c;
    int cur = 0;
    for (int t = 0; t < T_STEPS; ++t) {
        int* tok_cur = tokbuf + cur * B_SZ;
        int* tok_nxt = tokbuf + (1 - cur) * B_SZ;
        float* hn = hbuf + (size_t)(1 - cur) * B_SZ * H_SZ;
        float* cn = cbuf + (size_t)(1 - cur) * B_SZ * H_SZ;

        // gates = h @ W_hh^T + E_gates[tok]   [B x 4H]
        gemm_nt<false, true><<<dim3(G_SZ / 64, B_SZ / 64), blk, 0, stream>>>(
            hp, W_hh, gates, B_SZ, G_SZ, H_SZ, nullptr, nullptr, E_gates, tok_cur);

        // LSTM cell elementwise
        lstm_cell<<<(B_SZ * H_SZ) / 256, blk, 0, stream>>>(gates, cp, hn, cn);

        // logits = h_new @ W_out^T + b_out -> directly into d_out[t]
        float* logits = out + (size_t)t * B_SZ * V_SZ;
        gemm_nt<false, false><<<dim3(V_SZ / 64, B_SZ / 64), blk, 0, stream>>>(
            hn, W_out, logits, B_SZ, V_SZ, H_SZ, b_out, nullptr, nullptr, nullptr);

        // next token = argmax(logits)
        argmax_rows<<<B_SZ, blk, 0, stream>>>(logits, tok_nxt);

        hp = hn; cp = cn; cur = 1 - cur;
    }
}

// Round 2
// 2583.504 us; speedup vs baseline: 1.8193x; 1.8193x over previous
//
#include <hip/hip_runtime.h>
#include <math.h>

// Problem constants: T=64, B=1024, H=512, V=512
constexpr int T_STEPS = 64;
constexpr int B_SZ = 1024;
constexpr int H_SZ = 512;
constexpr int V_SZ = 512;
constexpr int G_SZ = 4 * H_SZ; // 2048

typedef _Float16 half8 __attribute__((ext_vector_type(8)));
typedef _Float16 half4 __attribute__((ext_vector_type(4)));
typedef float f32x4 __attribute__((ext_vector_type(4)));

__device__ __forceinline__ float4 ld4(const float* p) {
    return *reinterpret_cast<const float4*>(p);
}
__device__ __forceinline__ void st4(float* p, float4 v) {
    *reinterpret_cast<float4*>(p) = v;
}
__device__ __forceinline__ float sigf(float x) { return 1.f / (1.f + expf(-x)); }

// ---------------------------------------------------------------------------
// fp32 -> (hi fp16, lo fp16) split: x ~= hi + lo/2048
// ---------------------------------------------------------------------------
__global__ __launch_bounds__(256) void cvt_pair(
    const float* __restrict__ x, _Float16* __restrict__ hi,
    _Float16* __restrict__ lo)
{
    const int i4 = blockIdx.x * 256 + threadIdx.x; // float4 index
    const float4 v = ld4(x + (size_t)i4 * 4);
    half4 h, l;
    const float h0 = (float)(_Float16)v.x; h[0] = (_Float16)v.x; l[0] = (_Float16)((v.x - h0) * 2048.f);
    const float h1 = (float)(_Float16)v.y; h[1] = (_Float16)v.y; l[1] = (_Float16)((v.y - h1) * 2048.f);
    const float h2 = (float)(_Float16)v.z; h[2] = (_Float16)v.z; l[2] = (_Float16)((v.z - h2) * 2048.f);
    const float h3 = (float)(_Float16)v.w; h[3] = (_Float16)v.w; l[3] = (_Float16)((v.w - h3) * 2048.f);
    *reinterpret_cast<half4*>(hi + (size_t)i4 * 4) = h;
    *reinterpret_cast<half4*>(lo + (size_t)i4 * 4) = l;
}

// ---------------------------------------------------------------------------
// MFMA fp16x2 NT GEMM: Cpart[z][M][N] = A[M, k0:k0+kl] @ B[N, k0:k0+kl]^T
// A,B given as hi/lo fp16 arrays [rows][K] (K = full depth, row stride).
// Block: 128 threads (2 waves), tile BM=128 x BN=64, wave tile 64x64,
// BK=32 (one 16x16x32 MFMA per tile per iteration), K-split via blockIdx.z.
// ---------------------------------------------------------------------------
__global__ __launch_bounds__(128) void gemm_mfma(
    const _Float16* __restrict__ Ahi, const _Float16* __restrict__ Alo,
    const _Float16* __restrict__ Bhi, const _Float16* __restrict__ Blo,
    float* __restrict__ Cpart, int M, int N, int K, int kpart_len)
{
    constexpr int BM = 128, BN = 64, BK = 32;
    constexpr int LDK = 40; // padded LDS row (halves): 80B stride, breaks pow2 banks
    __shared__ __align__(16) _Float16 sAh[BM * LDK];
    __shared__ __align__(16) _Float16 sAl[BM * LDK];
    __shared__ __align__(16) _Float16 sBh[BN * LDK];
    __shared__ __align__(16) _Float16 sBl[BN * LDK];

    const int tid = threadIdx.x;
    const int wave = tid >> 6;
    const int lane = tid & 63;
    const int m0 = blockIdx.y * BM;
    const int n0 = blockIdx.x * BN;
    const int k0base = blockIdx.z * kpart_len;
    float* __restrict__ C = Cpart + (size_t)blockIdx.z * M * N;

    f32x4 accH[4][4] = {}; // hi*hi
    f32x4 accC[4][4] = {}; // hi*lo + lo*hi (scaled by 2048)

    const int lm = lane & 15;
    const int kq = lane >> 4;

    const int nIter = kpart_len / BK;
    for (int it = 0; it < nIter; ++it) {
        const int k0 = k0base + it * BK;
        // global loads into regs (chunk c: row=c>>2, kchunk=c&3, 16B each)
        half8 va[4], vA[4], vb[2], vB[2];
#pragma unroll
        for (int p = 0; p < 4; ++p) {
            const int c = tid + p * 128;
            const int r = c >> 2, kc = c & 3;
            const size_t off = (size_t)(m0 + r) * K + k0 + kc * 8;
            va[p] = *reinterpret_cast<const half8*>(Ahi + off);
            vA[p] = *reinterpret_cast<const half8*>(Alo + off);
        }
#pragma unroll
        for (int p = 0; p < 2; ++p) {
            const int c = tid + p * 128;
            const int r = c >> 2, kc = c & 3;
            const size_t off = (size_t)(n0 + r) * K + k0 + kc * 8;
            vb[p] = *reinterpret_cast<const half8*>(Bhi + off);
            vB[p] = *reinterpret_cast<const half8*>(Blo + off);
        }
        __syncthreads(); // previous iteration's LDS reads complete
#pragma unroll
        for (int p = 0; p < 4; ++p) {
            const int c = tid + p * 128;
            const int r = c >> 2, kc = c & 3;
            *reinterpret_cast<half8*>(&sAh[r * LDK + kc * 8]) = va[p];
            *reinterpret_cast<half8*>(&sAl[r * LDK + kc * 8]) = vA[p];
        }
#pragma unroll
        for (int p = 0; p < 2; ++p) {
            const int c = tid + p * 128;
            const int r = c >> 2, kc = c & 3;
            *reinterpret_cast<half8*>(&sBh[r * LDK + kc * 8]) = vb[p];
            *reinterpret_cast<half8*>(&sBl[r * LDK + kc * 8]) = vB[p];
        }
        __syncthreads();

        // B fragments (shared across gm)
        half8 bh[4], bl[4];
#pragma unroll
        for (int gn = 0; gn < 4; ++gn) {
            const int row = gn * 16 + lm;
            bh[gn] = *reinterpret_cast<const half8*>(&sBh[row * LDK + kq * 8]);
            bl[gn] = *reinterpret_cast<const half8*>(&sBl[row * LDK + kq * 8]);
        }
#pragma unroll
        for (int gm = 0; gm < 4; ++gm) {
            const int row = wave * 64 + gm * 16 + lm;
            const half8 ah = *reinterpret_cast<const half8*>(&sAh[row * LDK + kq * 8]);
            const half8 al = *reinterpret_cast<const half8*>(&sAl[row * LDK + kq * 8]);
#pragma unroll
            for (int gn = 0; gn < 4; ++gn)
                accH[gm][gn] = __builtin_amdgcn_mfma_f32_16x16x32_f16(ah, bh[gn], accH[gm][gn], 0, 0, 0);
#pragma unroll
            for (int gn = 0; gn < 4; ++gn)
                accC[gm][gn] = __builtin_amdgcn_mfma_f32_16x16x32_f16(ah, bl[gn], accC[gm][gn], 0, 0, 0);
#pragma unroll
            for (int gn = 0; gn < 4; ++gn)
                accC[gm][gn] = __builtin_amdgcn_mfma_f32_16x16x32_f16(al, bh[gn], accC[gm][gn], 0, 0, 0);
        }
    }

    // epilogue: C/D layout col=lane&15, row=(lane>>4)*4+reg
    const int lr = lane >> 4;
#pragma unroll
    for (int gm = 0; gm < 4; ++gm) {
#pragma unroll
        for (int gn = 0; gn < 4; ++gn) {
            const int mb = m0 + wave * 64 + gm * 16 + lr * 4;
            const int n = n0 + gn * 16 + lm;
#pragma unroll
            for (int r = 0; r < 4; ++r)
                C[(size_t)(mb + r) * N + n] =
                    accH[gm][gn][r] + accC[gm][gn][r] * (1.f / 2048.f);
        }
    }
}

// ---------------------------------------------------------------------------
// fp32 tiled NT GEMM (round-0 kernel) — used once for E_gates precompute
// ---------------------------------------------------------------------------
__global__ __launch_bounds__(256) void gemm_nt_f32(
    const float* __restrict__ A, const float* __restrict__ Bw,
    float* __restrict__ C, int M, int N, int K,
    const float* __restrict__ bias1, const float* __restrict__ bias2)
{
    constexpr int BM = 64, BN = 64, BK = 16;
    __shared__ __align__(16) float As[BK][BM];
    __shared__ __align__(16) float Bs[BK][BN];
    const int tid = threadIdx.x;
    const int tx = tid % 16, ty = tid / 16;
    const int m0 = blockIdx.y * BM, n0 = blockIdx.x * BN;
    const int lr = tid / 4, lc = (tid % 4) * 4;
    float acc[4][4] = {};
    for (int k0 = 0; k0 < K; k0 += BK) {
        const float4 av = ld4(&A[(size_t)(m0 + lr) * K + (k0 + lc)]);
        const float4 bv = ld4(&Bw[(size_t)(n0 + lr) * K + (k0 + lc)]);
        __syncthreads();
        As[lc + 0][lr] = av.x; As[lc + 1][lr] = av.y; As[lc + 2][lr] = av.z; As[lc + 3][lr] = av.w;
        Bs[lc + 0][lr] = bv.x; Bs[lc + 1][lr] = bv.y; Bs[lc + 2][lr] = bv.z; Bs[lc + 3][lr] = bv.w;
        __syncthreads();
#pragma unroll
        for (int k = 0; k < BK; ++k) {
            const float4 a4 = ld4(&As[k][ty * 4]);
            const float4 b4 = ld4(&Bs[k][tx * 4]);
            const float ar[4] = {a4.x, a4.y, a4.z, a4.w};
            const float br[4] = {b4.x, b4.y, b4.z, b4.w};
#pragma unroll
            for (int i = 0; i < 4; ++i)
#pragma unroll
                for (int j = 0; j < 4; ++j)
                    acc[i][j] = fmaf(ar[i], br[j], acc[i][j]);
        }
    }
    const int nc = n0 + tx * 4;
    const float4 b1 = ld4(&bias1[nc]);
    const float4 b2 = ld4(&bias2[nc]);
#pragma unroll
    for (int i = 0; i < 4; ++i) {
        const int m = m0 + ty * 4 + i;
        float4 v;
        v.x = acc[i][0] + b1.x + b2.x; v.y = acc[i][1] + b1.y + b2.y;
        v.z = acc[i][2] + b1.z + b2.z; v.w = acc[i][3] + b1.w + b2.w;
        st4(&C[(size_t)m * N + nc], v);
    }
}

// ---------------------------------------------------------------------------
// LSTM cell: gates = p0+p1+E_gates[tok[b]]; -> c (in-place), h_hi, h_lo
// one thread per 4 elements of [B, H]
// ---------------------------------------------------------------------------
__global__ __launch_bounds__(256) void cell_kernel(
    const float* __restrict__ p0, const float* __restrict__ p1,
    const float* __restrict__ Eg, const int* __restrict__ tok,
    float* __restrict__ c, _Float16* __restrict__ hhi, _Float16* __restrict__ hlo)
{
    const int i4 = blockIdx.x * 256 + threadIdx.x; // 0 .. B*H/4-1
    const int b = i4 >> 7;          // 128 float4 per row
    const int k = (i4 & 127) * 4;
    const size_t r0 = (size_t)b * G_SZ;
    const size_t re = (size_t)tok[b] * G_SZ;

    float4 gi, gf, gg, go;
    {
        float4 a, x, e;
        a = ld4(p0 + r0 + k);            x = ld4(p1 + r0 + k);            e = ld4(Eg + re + k);
        gi = make_float4(a.x + x.x + e.x, a.y + x.y + e.y, a.z + x.z + e.z, a.w + x.w + e.w);
        a = ld4(p0 + r0 + H_SZ + k);     x = ld4(p1 + r0 + H_SZ + k);     e = ld4(Eg + re + H_SZ + k);
        gf = make_float4(a.x + x.x + e.x, a.y + x.y + e.y, a.z + x.z + e.z, a.w + x.w + e.w);
        a = ld4(p0 + r0 + 2 * H_SZ + k); x = ld4(p1 + r0 + 2 * H_SZ + k); e = ld4(Eg + re + 2 * H_SZ + k);
        gg = make_float4(a.x + x.x + e.x, a.y + x.y + e.y, a.z + x.z + e.z, a.w + x.w + e.w);
        a = ld4(p0 + r0 + 3 * H_SZ + k); x = ld4(p1 + r0 + 3 * H_SZ + k); e = ld4(Eg + re + 3 * H_SZ + k);
        go = make_float4(a.x + x.x + e.x, a.y + x.y + e.y, a.z + x.z + e.z, a.w + x.w + e.w);
    }
    const size_t ci = (size_t)b * H_SZ + k;
    float4 cv = ld4(c + ci);
    float hn[4];
    {
        const float ii[4] = {gi.x, gi.y, gi.z, gi.w};
        const float ff[4] = {gf.x, gf.y, gf.z, gf.w};
        const float ggv[4] = {gg.x, gg.y, gg.z, gg.w};
        const float oo[4] = {go.x, go.y, go.z, go.w};
        float cc[4] = {cv.x, cv.y, cv.z, cv.w};
#pragma unroll
        for (int j = 0; j < 4; ++j) {
            const float cn = sigf(ff[j]) * cc[j] + sigf(ii[j]) * tanhf(ggv[j]);
            cc[j] = cn;
            hn[j] = sigf(oo[j]) * tanhf(cn);
        }
        st4(c + ci, make_float4(cc[0], cc[1], cc[2], cc[3]));
    }
    half4 h, l;
#pragma unroll
    for (int j = 0; j < 4; ++j) {
        const _Float16 hi = (_Float16)hn[j];
        h[j] = hi;
        l[j] = (_Float16)((hn[j] - (float)hi) * 2048.f);
    }
    *reinterpret_cast<half4*>(hhi + ci) = h;
    *reinterpret_cast<half4*>(hlo + ci) = l;
}

// ---------------------------------------------------------------------------
// combine 4 logit K-parts + b_out -> write out row + argmax -> tok
// one block (128 threads) per batch row
// ---------------------------------------------------------------------------
__global__ __launch_bounds__(128) void outmax_kernel(
    const float* __restrict__ lp, const float* __restrict__ b_out,
    float* __restrict__ outrow, int* __restrict__ tok)
{
    constexpr size_t PS = (size_t)B_SZ * V_SZ; // part stride
    const int b = blockIdx.x;
    const int t = threadIdx.x;
    const int col = t * 4;
    const size_t off = (size_t)b * V_SZ + col;
    float4 v0 = ld4(lp + off);
    const float4 v1 = ld4(lp + PS + off);
    const float4 v2 = ld4(lp + 2 * PS + off);
    const float4 v3 = ld4(lp + 3 * PS + off);
    const float4 bb = ld4(b_out + col);
    v0.x += v1.x + v2.x + v3.x + bb.x;
    v0.y += v1.y + v2.y + v3.y + bb.y;
    v0.z += v1.z + v2.z + v3.z + bb.z;
    v0.w += v1.w + v2.w + v3.w + bb.w;
    st4(outrow + off, v0);

    float bv = v0.x; int bi = col;
    if (v0.y > bv) { bv = v0.y; bi = col + 1; }
    if (v0.z > bv) { bv = v0.z; bi = col + 2; }
    if (v0.w > bv) { bv = v0.w; bi = col + 3; }
#pragma unroll
    for (int o = 32; o > 0; o >>= 1) {
        const float ov = __shfl_down(bv, o);
        const int oi = __shfl_down(bi, o);
        if (ov > bv || (ov == bv && oi < bi)) { bv = ov; bi = oi; }
    }
    __shared__ float sv[2];
    __shared__ int si[2];
    if ((t & 63) == 0) { sv[t >> 6] = bv; si[t >> 6] = bi; }
    __syncthreads();
    if (t == 0) {
        float fv = sv[0]; int fi = si[0];
        if (sv[1] > fv || (sv[1] == fv && si[1] < fi)) { fv = sv[1]; fi = si[1]; }
        tok[b] = fi;
    }
}

__global__ __launch_bounds__(256) void init_tok(int* __restrict__ tok)
{
    tok[blockIdx.x * blockDim.x + threadIdx.x] = 0; // SOS_INDEX
}

// ---------------------------------------------------------------------------
extern "C" void kernel_launch(void* const* d_in, const int* in_sizes, int n_in,
                              void* d_out, int out_size, void* d_ws, size_t ws_size,
                              hipStream_t stream)
{
    const float* enc_h = (const float*)d_in[2];
    const float* enc_c = (const float*)d_in[3];
    const float* emb   = (const float*)d_in[4];
    const float* W_ih  = (const float*)d_in[5];
    const float* W_hh  = (const float*)d_in[6];
    const float* b_ih  = (const float*)d_in[7];
    const float* b_hh  = (const float*)d_in[8];
    const float* W_out = (const float*)d_in[9];
    const float* b_out = (const float*)d_in[10];
    float* out = (float*)d_out;

    // ---- workspace layout (bytes, generous 16B alignment by construction)
    char* ws = (char*)d_ws;
    _Float16* Whh_hi = (_Float16*)(ws);                        // 2 MB
    _Float16* Whh_lo = (_Float16*)(ws + (2u << 20));           // 2 MB
    _Float16* Wout_hi = (_Float16*)(ws + (4u << 20));          // 0.5 MB
    _Float16* Wout_lo = (_Float16*)(ws + (4u << 20) + (512u << 10));
    _Float16* Hhi = (_Float16*)(ws + (5u << 20));              // 1 MB
    _Float16* Hlo = (_Float16*)(ws + (6u << 20));              // 1 MB
    float* cbuf   = (float*)(ws + (7u << 20));                 // 2 MB
    float* Eg     = (float*)(ws + (9u << 20));                 // 4 MB
    float* gparts = (float*)(ws + (13u << 20));                // 16 MB (2 parts)
    float* lparts = (float*)(ws + (29u << 20));                // 8 MB (4 parts)
    int*   tok    = (int*)(ws + (37u << 20));                  // 4 KB

    const dim3 blk256(256), blk128(128);

    // one-time per launch: fp16 hi/lo conversions
    cvt_pair<<<(2048 * 512) / 1024, blk256, 0, stream>>>(W_hh, Whh_hi, Whh_lo);
    cvt_pair<<<(512 * 512) / 1024, blk256, 0, stream>>>(W_out, Wout_hi, Wout_lo);
    cvt_pair<<<(1024 * 512) / 1024, blk256, 0, stream>>>(enc_h, Hhi, Hlo);
    hipMemcpyAsync(cbuf, enc_c, (size_t)B_SZ * H_SZ * 4, hipMemcpyDeviceToDevice, stream);
    init_tok<<<B_SZ / 256, blk256, 0, stream>>>(tok);

    // E_gates = emb @ W_ih^T + (b_ih + b_hh)   [V x 4H], fp32, once
    gemm_nt_f32<<<dim3(G_SZ / 64, V_SZ / 64), blk256, 0, stream>>>(
        emb, W_ih, Eg, V_SZ, G_SZ, H_SZ, b_ih, b_hh);

    for (int t = 0; t < T_STEPS; ++t) {
        // gates partials: [2][B][4H] = h @ W_hh^T (K split 2x256)
        gemm_mfma<<<dim3(G_SZ / 64, B_SZ / 128, 2), blk128, 0, stream>>>(
            Hhi, Hlo, Whh_hi, Whh_lo, gparts, B_SZ, G_SZ, H_SZ, 256);

        // cell: combine + gather E_gates[tok] + LSTM math -> c, h(hi/lo)
        cell_kernel<<<(B_SZ * H_SZ) / 1024, blk256, 0, stream>>>(
            gparts, gparts + (size_t)B_SZ * G_SZ, Eg, tok, cbuf, Hhi, Hlo);

        // logits partials: [4][B][V] = h_new @ W_out^T (K split 4x128)
        gemm_mfma<<<dim3(V_SZ / 64, B_SZ / 128, 4), blk128, 0, stream>>>(
            Hhi, Hlo, Wout_hi, Wout_lo, lparts, B_SZ, V_SZ, H_SZ, 128);

        // combine + bias + write out[t] + argmax -> tok
        outmax_kernel<<<B_SZ, blk128, 0, stream>>>(
            lparts, b_out, out + (size_t)t * B_SZ * V_SZ, tok);
    }
}

// Round 3
// 2302.148 us; speedup vs baseline: 2.0416x; 1.1222x over previous
//
#include <hip/hip_runtime.h>
#include <math.h>

// Problem constants: T=64, B=1024, H=512, V=512
constexpr int T_STEPS = 64;
constexpr int B_SZ = 1024;
constexpr int H_SZ = 512;
constexpr int V_SZ = 512;
constexpr int G_SZ = 4 * H_SZ; // 2048

typedef _Float16 half8 __attribute__((ext_vector_type(8)));
typedef _Float16 half4 __attribute__((ext_vector_type(4)));
typedef float f32x4 __attribute__((ext_vector_type(4)));

__device__ __forceinline__ float4 ld4(const float* p) {
    return *reinterpret_cast<const float4*>(p);
}
__device__ __forceinline__ void st4(float* p, float4 v) {
    *reinterpret_cast<float4*>(p) = v;
}
__device__ __forceinline__ float sigf(float x) { return 1.f / (1.f + expf(-x)); }

// packed argmax word: high 32 = orderable float key, low 32 = (511 - col)
__device__ __forceinline__ unsigned long long pack_vc(float v, int col) {
    unsigned u = __float_as_uint(v);
    unsigned key = (u & 0x80000000u) ? ~u : (u | 0x80000000u);
    return ((unsigned long long)key << 32) | (unsigned)(511 - col);
}

// ---------------------------------------------------------------------------
// fp32 -> (hi fp16, lo fp16) split: x ~= hi + lo/2048
// ---------------------------------------------------------------------------
__global__ __launch_bounds__(256) void cvt_pair(
    const float* __restrict__ x, _Float16* __restrict__ hi,
    _Float16* __restrict__ lo)
{
    const int i4 = blockIdx.x * 256 + threadIdx.x;
    const float4 v = ld4(x + (size_t)i4 * 4);
    half4 h, l;
    const float h0 = (float)(_Float16)v.x; h[0] = (_Float16)v.x; l[0] = (_Float16)((v.x - h0) * 2048.f);
    const float h1 = (float)(_Float16)v.y; h[1] = (_Float16)v.y; l[1] = (_Float16)((v.y - h1) * 2048.f);
    const float h2 = (float)(_Float16)v.z; h[2] = (_Float16)v.z; l[2] = (_Float16)((v.z - h2) * 2048.f);
    const float h3 = (float)(_Float16)v.w; h[3] = (_Float16)v.w; l[3] = (_Float16)((v.w - h3) * 2048.f);
    *reinterpret_cast<half4*>(hi + (size_t)i4 * 4) = h;
    *reinterpret_cast<half4*>(lo + (size_t)i4 * 4) = l;
}

// ---------------------------------------------------------------------------
// fp32 tiled NT GEMM — used once for E_gates = emb @ W_ih^T + (b_ih+b_hh)
// ---------------------------------------------------------------------------
__global__ __launch_bounds__(256) void gemm_nt_f32(
    const float* __restrict__ A, const float* __restrict__ Bw,
    float* __restrict__ C, int M, int N, int K,
    const float* __restrict__ bias1, const float* __restrict__ bias2)
{
    constexpr int BK = 16;
    __shared__ __align__(16) float As[BK][64];
    __shared__ __align__(16) float Bs[BK][64];
    const int tid = threadIdx.x;
    const int tx = tid % 16, ty = tid / 16;
    const int m0 = blockIdx.y * 64, n0 = blockIdx.x * 64;
    const int lr = tid / 4, lc = (tid % 4) * 4;
    float acc[4][4] = {};
    for (int k0 = 0; k0 < K; k0 += BK) {
        const float4 av = ld4(&A[(size_t)(m0 + lr) * K + (k0 + lc)]);
        const float4 bv = ld4(&Bw[(size_t)(n0 + lr) * K + (k0 + lc)]);
        __syncthreads();
        As[lc + 0][lr] = av.x; As[lc + 1][lr] = av.y; As[lc + 2][lr] = av.z; As[lc + 3][lr] = av.w;
        Bs[lc + 0][lr] = bv.x; Bs[lc + 1][lr] = bv.y; Bs[lc + 2][lr] = bv.z; Bs[lc + 3][lr] = bv.w;
        __syncthreads();
#pragma unroll
        for (int k = 0; k < BK; ++k) {
            const float4 a4 = ld4(&As[k][ty * 4]);
            const float4 b4 = ld4(&Bs[k][tx * 4]);
            const float ar[4] = {a4.x, a4.y, a4.z, a4.w};
            const float br[4] = {b4.x, b4.y, b4.z, b4.w};
#pragma unroll
            for (int i = 0; i < 4; ++i)
#pragma unroll
                for (int j = 0; j < 4; ++j)
                    acc[i][j] = fmaf(ar[i], br[j], acc[i][j]);
        }
    }
    const int nc = n0 + tx * 4;
    const float4 b1 = ld4(&bias1[nc]);
    const float4 b2 = ld4(&bias2[nc]);
#pragma unroll
    for (int i = 0; i < 4; ++i) {
        const int m = m0 + ty * 4 + i;
        float4 v;
        v.x = acc[i][0] + b1.x + b2.x; v.y = acc[i][1] + b1.y + b2.y;
        v.z = acc[i][2] + b1.z + b2.z; v.w = acc[i][3] + b1.w + b2.w;
        st4(&C[(size_t)m * N + nc], v);
    }
}

// ---------------------------------------------------------------------------
// Kernel A: gates GEMM (fp16x2 MFMA, full K) + LSTM cell, fused.
// Block: 256 thr (4 waves). Tile: 64 batch x (4 gates x 32 h-cols) => N=128.
// Wave (wm,wn): rows wm*32..+32, cols wn*64..+64. Grid (H/32=16, B/64=16).
// Epilogue: gate exchange via LDS (reused staging buffer), cell math,
// E_gates[tok] gather, h emitted as fp16 hi/lo, tok_reset cleared.
// ---------------------------------------------------------------------------
__global__ __launch_bounds__(256) void step_gates_cell(
    const _Float16* __restrict__ Ahi, const _Float16* __restrict__ Alo,
    const _Float16* __restrict__ Whh_hi, const _Float16* __restrict__ Whh_lo,
    const float* __restrict__ Eg,
    const unsigned long long* __restrict__ tok_cur,
    unsigned long long* __restrict__ tok_reset,
    float* __restrict__ cbuf,
    _Float16* __restrict__ Nhi, _Float16* __restrict__ Nlo)
{
    constexpr int LDK = 40; // padded LDS row in halves (80B)
    __shared__ __align__(16) char smem[64 * 129 * 4]; // 33024 B (>= staging 30720)
    _Float16* sAh = (_Float16*)smem;             // 64*40
    _Float16* sAl = sAh + 64 * LDK;
    _Float16* sBh = sAl + 64 * LDK;              // 128*40
    _Float16* sBl = sBh + 128 * LDK;
    float* sg = (float*)smem;                    // 64 x 129 (repurposed)

    const int tid = threadIdx.x;
    const int wave = tid >> 6, lane = tid & 63;
    const int wm = wave >> 1, wn = wave & 1;
    const int lm = lane & 15, kq = lane >> 4;
    const int h0 = blockIdx.x * 32;
    const int b0 = blockIdx.y * 64;

    // staging assignments
    const int ar = tid >> 2, akc = (tid & 3) * 8;            // A: 64 rows x 4 chunks
    const int r1 = tid >> 2, kc1 = (tid & 3) * 8;            // B chunk 1 (r 0..63)
    const int r2 = (tid + 256) >> 2, kc2 = kc1;              // B chunk 2 (r 64..127)
    const int g1 = (r1 >> 5) * 512 + h0 + (r1 & 31);         // W_hh row
    const int g2 = (r2 >> 5) * 512 + h0 + (r2 & 31);

    const _Float16* pAh = Ahi + (size_t)(b0 + ar) * 512 + akc;
    const _Float16* pAl = Alo + (size_t)(b0 + ar) * 512 + akc;
    const _Float16* pB1h = Whh_hi + (size_t)g1 * 512 + kc1;
    const _Float16* pB1l = Whh_lo + (size_t)g1 * 512 + kc1;
    const _Float16* pB2h = Whh_hi + (size_t)g2 * 512 + kc2;
    const _Float16* pB2l = Whh_lo + (size_t)g2 * 512 + kc2;

    f32x4 aH[2][4] = {};
    f32x4 aC[2][4] = {};

    for (int k0 = 0; k0 < 512; k0 += 32) {
        const half8 va_h = *(const half8*)(pAh + k0);
        const half8 va_l = *(const half8*)(pAl + k0);
        const half8 vb1h = *(const half8*)(pB1h + k0);
        const half8 vb1l = *(const half8*)(pB1l + k0);
        const half8 vb2h = *(const half8*)(pB2h + k0);
        const half8 vb2l = *(const half8*)(pB2l + k0);
        __syncthreads();
        *(half8*)(sAh + ar * LDK + akc) = va_h;
        *(half8*)(sAl + ar * LDK + akc) = va_l;
        *(half8*)(sBh + r1 * LDK + kc1) = vb1h;
        *(half8*)(sBl + r1 * LDK + kc1) = vb1l;
        *(half8*)(sBh + r2 * LDK + kc2) = vb2h;
        *(half8*)(sBl + r2 * LDK + kc2) = vb2l;
        __syncthreads();

        half8 bh[4], bl[4];
#pragma unroll
        for (int gn = 0; gn < 4; ++gn) {
            const int rr = wn * 64 + gn * 16 + lm;
            bh[gn] = *(const half8*)(sBh + rr * LDK + kq * 8);
            bl[gn] = *(const half8*)(sBl + rr * LDK + kq * 8);
        }
#pragma unroll
        for (int gm = 0; gm < 2; ++gm) {
            const int rm = wm * 32 + gm * 16 + lm;
            const half8 ah = *(const half8*)(sAh + rm * LDK + kq * 8);
            const half8 al = *(const half8*)(sAl + rm * LDK + kq * 8);
#pragma unroll
            for (int gn = 0; gn < 4; ++gn)
                aH[gm][gn] = __builtin_amdgcn_mfma_f32_16x16x32_f16(ah, bh[gn], aH[gm][gn], 0, 0, 0);
#pragma unroll
            for (int gn = 0; gn < 4; ++gn)
                aC[gm][gn] = __builtin_amdgcn_mfma_f32_16x16x32_f16(ah, bl[gn], aC[gm][gn], 0, 0, 0);
#pragma unroll
            for (int gn = 0; gn < 4; ++gn)
                aC[gm][gn] = __builtin_amdgcn_mfma_f32_16x16x32_f16(al, bh[gn], aC[gm][gn], 0, 0, 0);
        }
    }

    __syncthreads(); // staging reads done; repurpose smem as sg
#pragma unroll
    for (int gm = 0; gm < 2; ++gm) {
#pragma unroll
        for (int gn = 0; gn < 4; ++gn) {
            const int row = wm * 32 + gm * 16 + kq * 4;
            const int col = wn * 64 + gn * 16 + lm;
#pragma unroll
            for (int r = 0; r < 4; ++r)
                sg[(row + r) * 129 + col] =
                    aH[gm][gn][r] + aC[gm][gn][r] * (1.f / 2048.f);
        }
    }
    __syncthreads();

    // cell phase: thread -> row = tid>>2 (0..63), hh base = (tid&3)*8
    const int crow = tid >> 2;
    const int hb = (tid & 3) * 8;
    const int b = b0 + crow;
    const unsigned long long pk = tok_cur[b];
    const int tk = 511 - (int)(unsigned)(pk & 0xFFFFFFFFu);
    const float* egp = Eg + (size_t)tk * G_SZ + h0;

#pragma unroll
    for (int q = 0; q < 2; ++q) {
        const int hh = hb + q * 4;
        const float* sr = sg + crow * 129;
        const float4 gI = ld4(sr + hh);
        const float4 gF = ld4(sr + 32 + hh);
        const float4 gG = ld4(sr + 64 + hh);
        const float4 gO = ld4(sr + 96 + hh);
        const float4 eI = ld4(egp + hh);
        const float4 eF = ld4(egp + 512 + hh);
        const float4 eG = ld4(egp + 1024 + hh);
        const float4 eO = ld4(egp + 1536 + hh);
        const size_t ci = (size_t)b * 512 + h0 + hh;
        const float4 cv = ld4(cbuf + ci);

        const float iv[4] = {gI.x + eI.x, gI.y + eI.y, gI.z + eI.z, gI.w + eI.w};
        const float fv[4] = {gF.x + eF.x, gF.y + eF.y, gF.z + eF.z, gF.w + eF.w};
        const float gv[4] = {gG.x + eG.x, gG.y + eG.y, gG.z + eG.z, gG.w + eG.w};
        const float ov[4] = {gO.x + eO.x, gO.y + eO.y, gO.z + eO.z, gO.w + eO.w};
        float cc[4] = {cv.x, cv.y, cv.z, cv.w};
        float hn[4];
#pragma unroll
        for (int j = 0; j < 4; ++j) {
            const float cn = sigf(fv[j]) * cc[j] + sigf(iv[j]) * tanhf(gv[j]);
            cc[j] = cn;
            hn[j] = sigf(ov[j]) * tanhf(cn);
        }
        st4(cbuf + ci, make_float4(cc[0], cc[1], cc[2], cc[3]));
        half4 h, l;
#pragma unroll
        for (int j = 0; j < 4; ++j) {
            const _Float16 hi = (_Float16)hn[j];
            h[j] = hi;
            l[j] = (_Float16)((hn[j] - (float)hi) * 2048.f);
        }
        *reinterpret_cast<half4*>(Nhi + ci) = h;
        *reinterpret_cast<half4*>(Nlo + ci) = l;
    }

    if (blockIdx.x == 0 && tid < 64) tok_reset[b0 + tid] = 0ULL;
}

// ---------------------------------------------------------------------------
// Kernel B: logits GEMM (fp16x2 MFMA, LDS-free) + bias + out write + packed
// atomicMax argmax. Block 128 thr (2 waves), tile 32 batch x 64 V.
// Grid (V/64=8, B/32=32).
// ---------------------------------------------------------------------------
__global__ __launch_bounds__(128) void step_logits_argmax(
    const _Float16* __restrict__ Ahi, const _Float16* __restrict__ Alo,
    const _Float16* __restrict__ Whi, const _Float16* __restrict__ Wlo,
    const float* __restrict__ b_out,
    float* __restrict__ outT,
    unsigned long long* __restrict__ tokmax)
{
    const int tid = threadIdx.x, wave = tid >> 6, lane = tid & 63;
    const int lm = lane & 15, kq = lane >> 4;
    const int n0 = blockIdx.x * 64;
    const int m0 = blockIdx.y * 32 + wave * 16;

    f32x4 aH[4] = {};
    f32x4 aC[4] = {};

    const _Float16* pAh = Ahi + (size_t)(m0 + lm) * 512 + kq * 8;
    const _Float16* pAl = Alo + (size_t)(m0 + lm) * 512 + kq * 8;

    for (int k0 = 0; k0 < 512; k0 += 32) {
        const half8 ah = *(const half8*)(pAh + k0);
        const half8 al = *(const half8*)(pAl + k0);
        half8 bh[4], bl[4];
#pragma unroll
        for (int gn = 0; gn < 4; ++gn) {
            const size_t off = (size_t)(n0 + gn * 16 + lm) * 512 + k0 + kq * 8;
            bh[gn] = *(const half8*)(Whi + off);
            bl[gn] = *(const half8*)(Wlo + off);
        }
#pragma unroll
        for (int gn = 0; gn < 4; ++gn)
            aH[gn] = __builtin_amdgcn_mfma_f32_16x16x32_f16(ah, bh[gn], aH[gn], 0, 0, 0);
#pragma unroll
        for (int gn = 0; gn < 4; ++gn)
            aC[gn] = __builtin_amdgcn_mfma_f32_16x16x32_f16(ah, bl[gn], aC[gn], 0, 0, 0);
#pragma unroll
        for (int gn = 0; gn < 4; ++gn)
            aC[gn] = __builtin_amdgcn_mfma_f32_16x16x32_f16(al, bh[gn], aC[gn], 0, 0, 0);
    }

    unsigned long long best[4] = {0ULL, 0ULL, 0ULL, 0ULL};
#pragma unroll
    for (int gn = 0; gn < 4; ++gn) {
        const int col = n0 + gn * 16 + lm;
        const float bo = b_out[col];
#pragma unroll
        for (int r = 0; r < 4; ++r) {
            const float v = aH[gn][r] + aC[gn][r] * (1.f / 2048.f) + bo;
            const int row = m0 + kq * 4 + r;
            outT[(size_t)row * V_SZ + col] = v;
            const unsigned long long p = pack_vc(v, col);
            if (p > best[r]) best[r] = p;
        }
    }
#pragma unroll
    for (int r = 0; r < 4; ++r) {
#pragma unroll
        for (int off = 1; off < 16; off <<= 1) {
            const unsigned long long o = __shfl_xor(best[r], off);
            if (o > best[r]) best[r] = o;
        }
    }
    if (lm == 0) {
#pragma unroll
        for (int r = 0; r < 4; ++r)
            atomicMax(&tokmax[m0 + kq * 4 + r], best[r]);
    }
}

// ---------------------------------------------------------------------------
__global__ __launch_bounds__(256) void init_tok(unsigned long long* __restrict__ tok)
{
    const int i = blockIdx.x * 256 + threadIdx.x; // 0..2047
    tok[i] = (i < 1024) ? 511ULL : 0ULL; // buf0: token 0 (SOS); buf1: cleared
}

// ---------------------------------------------------------------------------
extern "C" void kernel_launch(void* const* d_in, const int* in_sizes, int n_in,
                              void* d_out, int out_size, void* d_ws, size_t ws_size,
                              hipStream_t stream)
{
    const float* enc_h = (const float*)d_in[2];
    const float* enc_c = (const float*)d_in[3];
    const float* emb   = (const float*)d_in[4];
    const float* W_ih  = (const float*)d_in[5];
    const float* W_hh  = (const float*)d_in[6];
    const float* b_ih  = (const float*)d_in[7];
    const float* b_hh  = (const float*)d_in[8];
    const float* W_out = (const float*)d_in[9];
    const float* b_out = (const float*)d_in[10];
    float* out = (float*)d_out;

    // workspace layout (1 MB units where convenient)
    char* ws = (char*)d_ws;
    _Float16* Whh_hi  = (_Float16*)(ws);                          // 2 MB
    _Float16* Whh_lo  = (_Float16*)(ws + (2u << 20));             // 2 MB
    _Float16* Wout_hi = (_Float16*)(ws + (4u << 20));             // 0.5 MB
    _Float16* Wout_lo = (_Float16*)(ws + (4u << 20) + (512u << 10));
    _Float16* Hhi[2] = {(_Float16*)(ws + (5u << 20)), (_Float16*)(ws + (7u << 20))};
    _Float16* Hlo[2] = {(_Float16*)(ws + (6u << 20)), (_Float16*)(ws + (8u << 20))};
    float* cbuf = (float*)(ws + (9u << 20));                      // 2 MB
    float* Eg   = (float*)(ws + (11u << 20));                     // 4 MB
    unsigned long long* tokbuf = (unsigned long long*)(ws + (15u << 20)); // 16 KB

    const dim3 blk256(256), blk128(128);

    // one-time conversions + init
    cvt_pair<<<(G_SZ * H_SZ) / 1024, blk256, 0, stream>>>(W_hh, Whh_hi, Whh_lo);
    cvt_pair<<<(V_SZ * H_SZ) / 1024, blk256, 0, stream>>>(W_out, Wout_hi, Wout_lo);
    cvt_pair<<<(B_SZ * H_SZ) / 1024, blk256, 0, stream>>>(enc_h, Hhi[0], Hlo[0]);
    hipMemcpyAsync(cbuf, enc_c, (size_t)B_SZ * H_SZ * 4, hipMemcpyDeviceToDevice, stream);
    init_tok<<<8, blk256, 0, stream>>>(tokbuf);

    // E_gates = emb @ W_ih^T + (b_ih + b_hh)   [V x 4H], fp32, once
    gemm_nt_f32<<<dim3(G_SZ / 64, V_SZ / 64), blk256, 0, stream>>>(
        emb, W_ih, Eg, V_SZ, G_SZ, H_SZ, b_ih, b_hh);

    for (int t = 0; t < T_STEPS; ++t) {
        const int cur = t & 1, nxt = (t + 1) & 1;
        // gates + cell: reads h[cur], tok[cur]; writes h[nxt], c, clears tok[nxt]
        step_gates_cell<<<dim3(H_SZ / 32, B_SZ / 64), blk256, 0, stream>>>(
            Hhi[cur], Hlo[cur], Whh_hi, Whh_lo, Eg,
            tokbuf + cur * B_SZ, tokbuf + nxt * B_SZ,
            cbuf, Hhi[nxt], Hlo[nxt]);

        // logits + argmax: reads h[nxt]; writes out[t], tok[nxt]
        step_logits_argmax<<<dim3(V_SZ / 64, B_SZ / 32), blk128, 0, stream>>>(
            Hhi[nxt], Hlo[nxt], Wout_hi, Wout_lo, b_out,
            out + (size_t)t * B_SZ * V_SZ, tokbuf + nxt * B_SZ);
    }
}